// Round 2
// baseline (420.085 us; speedup 1.0000x reference)
//
#include <hip/hip_runtime.h>

// Problem constants (from reference): B=128, C=2048, P=14 (so 196 pixels), R=36 boxes.
#define PDIM   14
#define PP     196          // P*P
#define C_ALL  2048
#define CTILE  64
#define NBOX   36
#define FC_SZ  (128 * 2048)                   // 262144
#define ATT_SZ (128 * 196 * 2048)             // 51380224

__global__ __launch_bounds__(256) void fused_feats_kernel(
    const float* __restrict__ images,   // [B, C, 14, 14]
    const float* __restrict__ boxes,    // [B, 36, 4] (x1,y1,x2,y2) normalized
    float* __restrict__ out)            // fc | att | bu concatenated
{
    // LDS tile: [pixel][channel] with 65-word row stride -> conflict-free for
    // (a) staging writes (consecutive lanes hit consecutive banks),
    // (b) transpose reads (fixed p, 64 consecutive c = 2-way free),
    // (c) fc reduce and box sums (same pattern as b).
    __shared__ float tile[PP][CTILE + 1];
    __shared__ int   bx1[NBOX], by1[NBOX], bx2[NBOX], by2[NBOX];
    __shared__ float barea[NBOX];
    __shared__ float part[4][CTILE];

    const int t   = threadIdx.x;
    const int bid = blockIdx.x;
    const int b   = bid >> 5;       // / (2048/64)
    const int c0  = (bid & 31) << 6;

    // ---- box coords: replicate jnp.round (half-to-even) + degenerate fix ----
    if (t < NBOX) {
        const float4 bv = *(const float4*)(boxes + ((size_t)b * NBOX + t) * 4);
        int x1 = (int)rintf(bv.x * 14.0f);
        int y1 = (int)rintf(bv.y * 14.0f);
        int x2 = (int)rintf(bv.z * 14.0f);
        int y2 = (int)rintf(bv.w * 14.0f);
        if (x1 == x2) { if (x2 < PDIM) x2++; else if (x1 > 0) x1--; }
        if (y1 == y2) { if (y2 < PDIM) y2++; else if (y1 > 0) y1--; }
        bx1[t] = x1; by1[t] = y1; bx2[t] = x2; by2[t] = y2;
        barea[t] = (float)((y2 - y1) * (x2 - x1));
    }

    // ---- stage 64 channels x 196 pixels (50 KB) via float4 loads ----
    // 196 % 4 == 0, so every float4 stays inside one channel row.
    const float4* src =
        (const float4*)(images + (size_t)b * C_ALL * PP + (size_t)c0 * PP);
    #pragma unroll
    for (int k = 0; k < 13; ++k) {
        int e = t + (k << 8);              // float4 index within the tile
        if (e < (CTILE * PP / 4)) {        // 3136
            float4 v = src[e];
            int c  = e / 49;               // 49 float4 per channel
            int pj = (e - c * 49) << 2;    // pixel index of v.x
            tile[pj + 0][c] = v.x;
            tile[pj + 1][c] = v.y;
            tile[pj + 2][c] = v.z;
            tile[pj + 3][c] = v.w;
        }
    }
    __syncthreads();

    const int cc = t & 63;
    const int w  = t >> 6;   // wave id 0..3

    // ---- att transpose writes, fused with fc partial sums ----
    // thread (w,cc) owns pixels p = w, w+4, ..., w+192 (49 of them); their sum
    // is exactly this thread's share of the channel's fc reduction.
    float* att = out + FC_SZ + (size_t)b * PP * C_ALL + c0;
    float s = 0.0f;
    #pragma unroll
    for (int k = 0; k < 49; ++k) {
        int p = w + (k << 2);
        float v = tile[p][cc];
        att[(size_t)p * C_ALL + cc] = v;   // 64 consecutive floats per wave
        s += v;
    }
    part[w][cc] = s;
    __syncthreads();

    if (t < CTILE) {
        float fsum = part[0][t] + part[1][t] + part[2][t] + part[3][t];
        out[(size_t)b * C_ALL + c0 + t] = fsum / 196.0f;
    }

    // ---- bu: per-box average; each wave owns one box per iteration ----
    float* bu = out + FC_SZ + ATT_SZ + (size_t)b * NBOX * C_ALL + c0;
    #pragma unroll
    for (int k = 0; k < 9; ++k) {
        int pair = t + (k << 8);           // (r, cc) pair
        int r = pair >> 6;                 // same r across the whole wave
        int x1 = bx1[r], y1 = by1[r], x2 = bx2[r], y2 = by2[r];
        float bs = 0.0f;
        for (int i = y1; i < y2; ++i)
            for (int j = x1; j < x2; ++j)
                bs += tile[i * PDIM + j][cc];
        bu[(size_t)r * C_ALL + cc] = bs / barea[r];
    }
}

extern "C" void kernel_launch(void* const* d_in, const int* in_sizes, int n_in,
                              void* d_out, int out_size, void* d_ws, size_t ws_size,
                              hipStream_t stream) {
    const float* images = (const float*)d_in[0];
    const float* boxes  = (const float*)d_in[1];
    float* out          = (float*)d_out;
    // grid: B (128) x channel-tiles (2048/64 = 32) = 4096 blocks
    hipLaunchKernelGGL(fused_feats_kernel, dim3(4096), dim3(256), 0, stream,
                       images, boxes, out);
}

// Round 7
// 414.263 us; speedup vs baseline: 1.0141x; 1.0141x over previous
//
#include <hip/hip_runtime.h>

// B=128, C=2048, P=14 (196 px), R=36 boxes.
#define PDIM   14
#define PP     196
#define C_ALL  2048
#define CT     32            // channels per block
#define ROW    36            // [pixel][channel] row stride in words; 144B = 16B-aligned
#define NBOX   36
#define FC_SZ  (128 * 2048)
#define ATT_SZ (128 * 196 * 2048)

__global__ __launch_bounds__(256, 5) void fused_feats_kernel(
    const float* __restrict__ images,   // [B, C, 14, 14]
    const float* __restrict__ boxes,    // [B, 36, 4]
    float* __restrict__ out)            // fc | att | bu
{
    __shared__ float tile[PP * ROW];    // 28,224 B; [p][c] so c is contiguous
    __shared__ float part[4][CT];       // fc partials per wave, 512 B
    __shared__ int   boxp[NBOX];        // packed box coords, 144 B
    // total 28,880 B -> 5 blocks/CU (20 waves), vs 3 blocks before

    const int t  = threadIdx.x;
    const int b  = blockIdx.x >> 6;     // 64 channel-tiles per batch
    const int c0 = (blockIdx.x & 63) << 5;

    // ---- boxes: jnp.round (half-even) == rintf; degenerate fix as reference ----
    if (t < NBOX) {
        const float4 bv = *(const float4*)(boxes + ((size_t)b * NBOX + t) * 4);
        int x1 = (int)rintf(bv.x * 14.0f);
        int y1 = (int)rintf(bv.y * 14.0f);
        int x2 = (int)rintf(bv.z * 14.0f);
        int y2 = (int)rintf(bv.w * 14.0f);
        if (x1 == x2) { if (x2 < PDIM) x2++; else if (x1 > 0) x1--; }
        if (y1 == y2) { if (y2 < PDIM) y2++; else if (y1 > 0) y1--; }
        boxp[t] = x1 | (y1 << 8) | (x2 << 16) | (y2 << 24);
    }

    // ---- stage 32 ch x 196 px. Lane map: cL fast (t&15) -> LDS writes are
    // bank-conflict-free (16 consecutive words per group; 4-px row stride of
    // 144 words ≡ 16 banks -> adjacent groups tile all 32 banks, 2-way free).
    // Global: per wave 16 channel-rows x 64 contiguous bytes -> full lines.
    const float4* src =
        (const float4*)(images + (size_t)b * C_ALL * PP + (size_t)c0 * PP);
    #pragma unroll
    for (int k = 0; k < 7; ++k) {
        int tau = t + (k << 8);
        if (tau < CT * 49) {                 // 1568 float4 per block
            int cL   = tau & 15;
            int rest = tau >> 4;
            int j4   = rest % 49;            // float4 index within channel row
            int c    = ((rest / 49) << 4) + cL;
            float4 v = src[c * 49 + j4];
            int p0 = j4 << 2;
            tile[(p0 + 0) * ROW + c] = v.x;
            tile[(p0 + 1) * ROW + c] = v.y;
            tile[(p0 + 2) * ROW + c] = v.z;
            tile[(p0 + 3) * ROW + c] = v.w;
        }
    }
    __syncthreads();

    // ---- att: float4 per lane (4 consecutive channels @ one pixel), fused fc ----
    float4 acc = {0.f, 0.f, 0.f, 0.f};
    float* att = out + FC_SZ + (size_t)b * PP * C_ALL + c0;
    #pragma unroll
    for (int k = 0; k < 7; ++k) {
        int tau = t + (k << 8);
        if (tau < PP * 8) {                  // 196 px * 8 quads
            int p = tau >> 3, l = tau & 7;   // l == t&7, constant per thread
            float4 v = *(const float4*)(tile + p * ROW + (l << 2));
            *(float4*)(att + (size_t)p * C_ALL + (l << 2)) = v;
            acc.x += v.x; acc.y += v.y; acc.z += v.z; acc.w += v.w;
        }
    }
    // reduce across the 8 lanes per wave sharing quad l (xor 8,16,32)
    #pragma unroll
    for (int m = 8; m < 64; m <<= 1) {
        acc.x += __shfl_xor(acc.x, m);
        acc.y += __shfl_xor(acc.y, m);
        acc.z += __shfl_xor(acc.z, m);
        acc.w += __shfl_xor(acc.w, m);
    }
    if ((t & 63) < 8)
        ((float4*)part)[(t >> 6) * 8 + (t & 7)] = acc;
    __syncthreads();
    if (t < CT) {
        float s = part[0][t] + part[1][t] + part[2][t] + part[3][t];
        out[(size_t)b * C_ALL + c0 + t] = s * (1.0f / 196.0f);
    }

    // ---- bu: (box, channel) tasks; 32 consecutive channels per half-wave ----
    float* bu = out + FC_SZ + ATT_SZ + (size_t)b * NBOX * C_ALL + c0;
    #pragma unroll
    for (int k = 0; k < 5; ++k) {
        int tau = t + (k << 8);
        if (tau < NBOX * CT) {               // 1152 tasks
            int r = tau >> 5, cc = tau & 31;
            int pk = boxp[r];
            int x1 = pk & 255, y1 = (pk >> 8) & 255;
            int x2 = (pk >> 16) & 255, y2 = pk >> 24;
            float s = 0.f;
            for (int i = y1; i < y2; ++i) {
                const float* rowp = tile + (i * PDIM) * ROW + cc;
                for (int j = x1; j < x2; ++j)
                    s += rowp[j * ROW];
            }
            bu[(size_t)r * C_ALL + cc] = s / (float)((y2 - y1) * (x2 - x1));
        }
    }
}

extern "C" void kernel_launch(void* const* d_in, const int* in_sizes, int n_in,
                              void* d_out, int out_size, void* d_ws, size_t ws_size,
                              hipStream_t stream) {
    const float* images = (const float*)d_in[0];
    const float* boxes  = (const float*)d_in[1];
    float* out          = (float*)d_out;
    // 128 batches x 64 channel-tiles = 8192 blocks
    hipLaunchKernelGGL(fused_feats_kernel, dim3(8192), dim3(256), 0, stream,
                       images, boxes, out);
}